// Round 3
// baseline (106.860 us; speedup 1.0000x reference)
//
#include <hip/hip_runtime.h>
#include <hip/hip_fp16.h>

#define BN 4096
#define DIM 256
#define NBLK 32              // 4096/128 row-blocks
#define NPAIR 528            // NBLK*(NBLK+1)/2 upper-tri block pairs
#define MARGIN_F 0.3f
#define NEG_FILL_F 1e9f
#define HP_SENT_BITS 0xBF800000  // bits of -1.0f: "no positive seen"

typedef __attribute__((ext_vector_type(8))) _Float16 f16x8;
typedef __attribute__((ext_vector_type(4))) float f32x4;

// ---------------- prep: norms (exact fp32) + sentinel/red init + fp16 panel ------
// Eh global layout is chunk-major: [kc = k/8][row][8 f16], 16B per (kc,row) chunk.
// Stores staged through LDS: 16B/lane, 4-row (64B) contiguity per kc.
__global__ __launch_bounds__(256) void tl_prep(const float* __restrict__ E,
                                               float* __restrict__ norms,
                                               float* __restrict__ red,
                                               int* __restrict__ hp2i,
                                               unsigned* __restrict__ hn2u,
                                               ushort* __restrict__ Eh) {
    __shared__ ushort sh[4][272];            // 272-pad: 544B row stride, 16B-aligned
    const int tid  = threadIdx.x;
    const int lane = tid & 63;
    const int wrow = tid >> 6;               // 0..3: row within block
    const int row0 = blockIdx.x * 4;
    const int row  = row0 + wrow;

    float4 v = reinterpret_cast<const float4*>(E + (size_t)row * DIM)[lane];
    float f[4] = {v.x, v.y, v.z, v.w};
    ushort hb[4];
    float s = 0.0f;
    #pragma unroll
    for (int q = 0; q < 4; ++q) {
        s += f[q] * f[q];                       // norm from ORIGINAL fp32 (exact)
        hb[q] = __half_as_ushort(__float2half(f[q]));   // RN convert
    }
    // lane holds cols lane*4..lane*4+3 -> LDS row-major (2-way bank alias: free)
    *reinterpret_cast<ushort4*>(&sh[wrow][lane * 4]) = make_ushort4(hb[0], hb[1], hb[2], hb[3]);

    #pragma unroll
    for (int m = 32; m; m >>= 1) s += __shfl_xor(s, m, 64);
    if (lane == 0) norms[row] = s;
    if (tid < 4) {                               // sentinel init for this block's rows
        hp2i[row0 + tid] = (int)HP_SENT_BITS;
        hn2u[row0 + tid] = __float_as_uint(NEG_FILL_F);
    }
    if (blockIdx.x == 0 && tid < 3) red[tid] = 0.0f;  // [2] = ticket

    __syncthreads();
    // 4 rows x 32 kc = 128 chunks of 16B; threads 0..127, rows fastest -> 64B runs
    if (tid < 128) {
        const int kc = tid >> 2, r = tid & 3;
        const f16x8 frag = *reinterpret_cast<const f16x8*>(&sh[r][kc * 8]);
        *reinterpret_cast<f16x8*>(Eh + (((size_t)(kc * BN + row0 + r)) << 3)) = frag;
    }
}

// ---------------- main: barrier-free fp16 MFMA Gram + full fused reduction -------
// One block per upper-tri 128x128 pair, 4 waves each owning a 64x64 sub-tile.
// Eh (2 MB) is L3-resident: fragments loaded straight from global, register
// double-buffered over 8 K=32 steps. NO operand LDS, NO main-loop barriers.
// __launch_bounds__(256,3): <=~170 VGPR -> 3 blocks/CU -> all 528 blocks resident.
// Block results -> device-scope atomics on hp2/hn2[4096] (monotone int/uint
// encodings, coherent across XCDs); last block (ticket) computes the loss.
__global__ __launch_bounds__(256, 3) void tl_main(const ushort* __restrict__ Eh,
                                                  const int* __restrict__ labels,
                                                  const float* __restrict__ norms,
                                                  int* __restrict__ hp2i,
                                                  unsigned* __restrict__ hn2u,
                                                  float* __restrict__ red,
                                                  float* __restrict__ out) {
    __shared__ int comb[512];            // [0:128) rHP [128) rHN [256) cHP [384) cHN
    __shared__ unsigned lastFlag;
    __shared__ float redS[4], redC[4];

    const int tid  = threadIdx.x;
    const int lane = tid & 63;
    const int wave = tid >> 6;
    const int wy = wave >> 1, wx = wave & 1;
    const int quad = lane >> 4, l15 = lane & 15;

    // decode blockIdx -> (ib <= jb) upper-tri pair
    int t = blockIdx.x, ib = 0, off = 0;
    while (off + (NBLK - ib) <= t) { off += NBLK - ib; ++ib; }
    const int jb = ib + (t - off);
    const int i0 = ib * 128, j0 = jb * 128;

    f32x4 acc[4][4];
    #pragma unroll
    for (int r = 0; r < 4; ++r)
        #pragma unroll
        for (int c = 0; c < 4; ++c)
            acc[r][c] = (f32x4){0.f, 0.f, 0.f, 0.f};

    // per-lane fragment addresses: chunk (s*4 + quad), rows below (ushort units)
    const ushort* baseQ = Eh + (size_t)quad * (BN * 8);
    int rA[4], rB[4];
    #pragma unroll
    for (int r = 0; r < 4; ++r) rA[r] = (i0 + wy * 64 + r * 16 + l15) * 8;
    #pragma unroll
    for (int c = 0; c < 4; ++c) rB[c] = (j0 + wx * 64 + c * 16 + l15) * 8;

    f16x8 a0[4], b0[4], a1[4], b1[4];
    auto LD = [&](f16x8 (&A)[4], f16x8 (&B)[4], int s) {
        const size_t so = (size_t)s * (4u * BN * 8u);
        #pragma unroll
        for (int r = 0; r < 4; ++r)
            A[r] = *reinterpret_cast<const f16x8*>(baseQ + so + (size_t)rA[r]);
        #pragma unroll
        for (int c = 0; c < 4; ++c)
            B[c] = *reinterpret_cast<const f16x8*>(baseQ + so + (size_t)rB[c]);
    };
    auto MM = [&](f16x8 (&A)[4], f16x8 (&B)[4]) {
        #pragma unroll
        for (int c = 0; c < 4; ++c)
            #pragma unroll
            for (int r = 0; r < 4; ++r)
                acc[r][c] = __builtin_amdgcn_mfma_f32_16x16x32_f16(A[r], B[c], acc[r][c], 0, 0, 0);
    };

    // software pipeline: loads of step s+1 in flight under MFMAs of step s
    LD(a0, b0, 0);
    LD(a1, b1, 1); MM(a0, b0);
    LD(a0, b0, 2); MM(a1, b1);
    LD(a1, b1, 3); MM(a0, b0);
    LD(a0, b0, 4); MM(a1, b1);
    LD(a1, b1, 5); MM(a0, b0);
    LD(a0, b0, 6); MM(a1, b1);
    LD(a1, b1, 7); MM(a0, b0);
    MM(a1, b1);

    // ---- epilogue: dots -> d^2 -> masked row & col stats (d^2 space; sqrt later)
    // C layout (16x16x32): col = lane&15, row = quad*4 + reg  [m89/m91, dtype-indep]
    const int rowBase = i0 + wy * 64;
    const int colBase = j0 + wx * 64;

    float nrow[4][4]; int lrow[4][4];
    #pragma unroll
    for (int r = 0; r < 4; ++r)
        #pragma unroll
        for (int e = 0; e < 4; ++e) {
            const int g = rowBase + r * 16 + quad * 4 + e;
            nrow[r][e] = norms[g];
            lrow[r][e] = labels[g];
        }
    float ncol[4]; int lcol[4];
    #pragma unroll
    for (int c = 0; c < 4; ++c) {
        const int g = colBase + c * 16 + l15;
        ncol[c] = norms[g];
        lcol[c] = labels[g];
    }

    float rmax[4][4], rmin[4][4], cmax[4], cmin[4];
    #pragma unroll
    for (int r = 0; r < 4; ++r)
        #pragma unroll
        for (int e = 0; e < 4; ++e) { rmax[r][e] = -1.0f; rmin[r][e] = NEG_FILL_F; }
    #pragma unroll
    for (int c = 0; c < 4; ++c) { cmax[c] = -1.0f; cmin[c] = NEG_FILL_F; }

    #pragma unroll
    for (int c = 0; c < 4; ++c) {
        const int gcol = colBase + c * 16 + l15;
        #pragma unroll
        for (int r = 0; r < 4; ++r) {
            #pragma unroll
            for (int e = 0; e < 4; ++e) {
                const int grow = rowBase + r * 16 + quad * 4 + e;
                float d2 = nrow[r][e] + ncol[c] - 2.0f * acc[r][c][e];
                d2 = fmaxf(d2, 0.0f);            // d==0 <=> d2==0: guard-free
                if (lrow[r][e] == lcol[c]) {
                    if (grow != gcol) {
                        rmax[r][e] = fmaxf(rmax[r][e], d2);
                        cmax[c]    = fmaxf(cmax[c], d2);
                    }
                } else {
                    rmin[r][e] = fminf(rmin[r][e], d2);
                    cmin[c]    = fminf(cmin[c], d2);
                }
            }
        }
    }

    #pragma unroll
    for (int m = 1; m <= 8; m <<= 1) {          // row stats across lane bits 0..3
        #pragma unroll
        for (int r = 0; r < 4; ++r)
            #pragma unroll
            for (int e = 0; e < 4; ++e) {
                rmax[r][e] = fmaxf(rmax[r][e], __shfl_xor(rmax[r][e], m, 64));
                rmin[r][e] = fminf(rmin[r][e], __shfl_xor(rmin[r][e], m, 64));
            }
    }
    #pragma unroll
    for (int m = 16; m <= 32; m <<= 1) {        // col stats across quads
        #pragma unroll
        for (int c = 0; c < 4; ++c) {
            cmax[c] = fmaxf(cmax[c], __shfl_xor(cmax[c], m, 64));
            cmin[c] = fminf(cmin[c], __shfl_xor(cmin[c], m, 64));
        }
    }

    // block-level combine in LDS (CU-local atomics; signed-int encoding so the
    // -1.0f sentinel orders correctly), then device-scope global atomics.
    int*      srhp = comb;                                   // [128]
    unsigned* srhn = reinterpret_cast<unsigned*>(comb + 128);
    int*      schp = comb + 256;
    unsigned* schn = reinterpret_cast<unsigned*>(comb + 384);
    if (tid < 128) {
        srhp[tid] = (int)HP_SENT_BITS;
        srhn[tid] = __float_as_uint(NEG_FILL_F);
        schp[tid] = (int)HP_SENT_BITS;
        schn[tid] = __float_as_uint(NEG_FILL_F);
    }
    __syncthreads();
    if (l15 == 0) {   // lanes 0,16,32,48 hold row results for their quad
        #pragma unroll
        for (int r = 0; r < 4; ++r)
            #pragma unroll
            for (int e = 0; e < 4; ++e) {
                const int lr = wy * 64 + r * 16 + quad * 4 + e;
                atomicMax(&srhp[lr], __float_as_int(rmax[r][e]));
                atomicMin(&srhn[lr], __float_as_uint(rmin[r][e]));
            }
    }
    if (quad == 0) {  // lanes 0..15 hold col results
        #pragma unroll
        for (int c = 0; c < 4; ++c) {
            const int lc = wx * 64 + c * 16 + l15;
            atomicMax(&schp[lc], __float_as_int(cmax[c]));
            atomicMin(&schn[lc], __float_as_uint(cmin[c]));
        }
    }
    __syncthreads();
    if (tid < 128) {
        int      rp = srhp[tid];
        unsigned rn = srhn[tid];
        const int      cp = schp[tid];
        const unsigned cn = schn[tid];
        if (ib == jb) {   // diagonal: combine row & col parts first
            rp = max(rp, cp);
            rn = min(rn, cn);
            if (rp != (int)HP_SENT_BITS) atomicMax(&hp2i[i0 + tid], rp);
            atomicMin(&hn2u[i0 + tid], rn);
        } else {
            if (rp != (int)HP_SENT_BITS) atomicMax(&hp2i[i0 + tid], rp);
            atomicMin(&hn2u[i0 + tid], rn);
            if (cp != (int)HP_SENT_BITS) atomicMax(&hp2i[j0 + tid], cp);
            atomicMin(&hn2u[j0 + tid], cn);
        }
    }

    // ---- last-block final reduction (ticket pattern) ----
    __threadfence();                  // release this block's atomics
    __syncthreads();                  // (barrier also drains each wave's vmem)
    if (tid == 0) {
        const unsigned ticket = atomicAdd(reinterpret_cast<unsigned*>(&red[2]), 1u);
        lastFlag = (ticket == NPAIR - 1) ? 1u : 0u;
    }
    __syncthreads();
    if (lastFlag) {
        float s_ = 0.0f, c_ = 0.0f;
        #pragma unroll
        for (int q = 0; q < BN / 256; ++q) {     // 16 rows per thread
            const int r = q * 256 + tid;
            // identity-RMW atomic reads: guaranteed coherent vs all blocks' atomics
            const int      hpB = atomicMax(&hp2i[r], (int)0x80000000);
            const unsigned hnB = atomicMin(&hn2u[r], 0xFFFFFFFFu);
            const float hp2 = __int_as_float(hpB);
            const float hn2 = __uint_as_float(hnB);
            if (hp2 >= 0.0f && hn2 < NEG_FILL_F) {           // has_pos && has_neg
                s_ += fmaxf(sqrtf(hp2) - sqrtf(hn2) + MARGIN_F, 0.0f);
                c_ += 1.0f;
            }
        }
        #pragma unroll
        for (int m = 32; m; m >>= 1) {
            s_ += __shfl_xor(s_, m, 64);
            c_ += __shfl_xor(c_, m, 64);
        }
        if (lane == 0) { redS[wave] = s_; redC[wave] = c_; }
        __syncthreads();
        if (tid == 0) {
            const float S = redS[0] + redS[1] + redS[2] + redS[3];
            const float C = redC[0] + redC[1] + redC[2] + redC[3];
            out[0] = (C > 0.0f) ? (S / fmaxf(C, 1.0f)) : 0.0f;
        }
    }
}

extern "C" void kernel_launch(void* const* d_in, const int* in_sizes, int n_in,
                              void* d_out, int out_size, void* d_ws, size_t ws_size,
                              hipStream_t stream) {
    const float* E      = (const float*)d_in[0];
    const int*   labels = (const int*)d_in[1];

    float*    ws    = (float*)d_ws;
    float*    norms = ws;                          // [4096] f32
    float*    red   = ws + 4096;                   // [3] f32 ([2] = ticket)
    int*      hp2i  = (int*)(ws + 8192);           // [4096] hardest-pos d^2 (int enc)
    unsigned* hn2u  = (unsigned*)(ws + 12288);     // [4096] hardest-neg d^2 (uint enc)
    ushort*   Eh    = (ushort*)(ws + 16384);       // [32][4096][8] f16 = 2 MB

    tl_prep<<<BN / 4, 256, 0, stream>>>(E, norms, red, hp2i, hn2u, Eh);
    tl_main<<<NPAIR, 256, 0, stream>>>(Eh, labels, norms, hp2i, hn2u, red, (float*)d_out);
}

// Round 4
// 79.363 us; speedup vs baseline: 1.3465x; 1.3465x over previous
//
#include <hip/hip_runtime.h>
#include <hip/hip_fp16.h>

#define BN 4096
#define DIM 256
#define NBLK 32              // 4096/128 row-blocks
#define NPAIR 528            // NBLK*(NBLK+1)/2 upper-tri block pairs
#define MARGIN_F 0.3f
#define NEG_FILL_F 1e9f
#define HP_SENT_BITS 0xBF800000  // bits of -1.0f: "no positive seen"

typedef __attribute__((ext_vector_type(8))) _Float16 f16x8;
typedef __attribute__((ext_vector_type(4))) float f32x4;

// ---------------- prep: norms (exact fp32) + red zero + fp16 panel ---------------
// Eh global layout is chunk-major: [kc = k/8][row][8 f16], 16B per (kc,row) chunk.
// Stores staged through LDS: 16B/lane, 4-row (64B) contiguity per kc.
__global__ __launch_bounds__(256) void tl_prep(const float* __restrict__ E,
                                               float* __restrict__ norms,
                                               float* __restrict__ red,
                                               ushort* __restrict__ Eh) {
    __shared__ ushort sh[4][272];            // 272-pad: 544B row stride, 16B-aligned
    const int tid  = threadIdx.x;
    const int lane = tid & 63;
    const int wrow = tid >> 6;               // 0..3: row within block
    const int row0 = blockIdx.x * 4;
    const int row  = row0 + wrow;

    float4 v = reinterpret_cast<const float4*>(E + (size_t)row * DIM)[lane];
    float f[4] = {v.x, v.y, v.z, v.w};
    ushort hb[4];
    float s = 0.0f;
    #pragma unroll
    for (int q = 0; q < 4; ++q) {
        s += f[q] * f[q];                       // norm from ORIGINAL fp32 (exact)
        hb[q] = __half_as_ushort(__float2half(f[q]));   // RN convert
    }
    // lane holds cols lane*4..lane*4+3 -> LDS row-major (2-way bank alias: free)
    *reinterpret_cast<ushort4*>(&sh[wrow][lane * 4]) = make_ushort4(hb[0], hb[1], hb[2], hb[3]);

    #pragma unroll
    for (int m = 32; m; m >>= 1) s += __shfl_xor(s, m, 64);
    if (lane == 0) norms[row] = s;
    if (blockIdx.x == 0 && tid < 3) red[tid] = 0.0f;  // [0]=sum [1]=cnt [2]=ticket

    __syncthreads();
    // 4 rows x 32 kc = 128 chunks of 16B; threads 0..127, rows fastest -> 64B runs
    if (tid < 128) {
        const int kc = tid >> 2, r = tid & 3;
        const f16x8 frag = *reinterpret_cast<const f16x8*>(&sh[r][kc * 8]);
        *reinterpret_cast<f16x8*>(Eh + (((size_t)(kc * BN + row0 + r)) << 3)) = frag;
    }
}

// ---------------- main: fp16 MFMA Gram, operands direct from L2, 4 waves/SIMD ----
// One block per upper-tri 128x128 pair, 4 waves each owning a 64x64 sub-tile.
// Eh (2 MB) is L2-resident: fragments loaded straight from global.
// SINGLE-buffered fragments + __launch_bounds__(256,4): combined regs <=128
// (acc 64 AGPR + frags 32 + addr ~16) -> 4 waves/SIMD (was 144 regs -> 2/SIMD,
// the hard occupancy step at the 128-reg boundary, m69). Latency hiding moves
// from ILP (dbuf) to TLP (2x resident waves) -- all pipes were <10% busy.
// Results leave via PLAIN stores to collision-free partial slots (device-scope
// atomic fan-in in round 3 cost +20us; reverted).
__global__ __launch_bounds__(256, 4) void tl_main(const ushort* __restrict__ Eh,
                                                  const int* __restrict__ labels,
                                                  const float* __restrict__ norms,
                                                  float* __restrict__ pHP,
                                                  float* __restrict__ pHN) {
    __shared__ int comb[512];            // [0:128) rHP [128) rHN [256) cHP [384) cHN

    const int tid  = threadIdx.x;
    const int lane = tid & 63;
    const int wave = tid >> 6;
    const int wy = wave >> 1, wx = wave & 1;
    const int quad = lane >> 4, l15 = lane & 15;

    // decode blockIdx -> (ib <= jb) upper-tri pair
    int t = blockIdx.x, ib = 0, off = 0;
    while (off + (NBLK - ib) <= t) { off += NBLK - ib; ++ib; }
    const int jb = ib + (t - off);
    const int i0 = ib * 128, j0 = jb * 128;

    f32x4 acc[4][4];
    #pragma unroll
    for (int r = 0; r < 4; ++r)
        #pragma unroll
        for (int c = 0; c < 4; ++c)
            acc[r][c] = (f32x4){0.f, 0.f, 0.f, 0.f};

    // per-lane fragment addresses: chunk (s*4 + quad), rows below (ushort units)
    const ushort* baseQ = Eh + (size_t)quad * (BN * 8);
    int rA[4], rB[4];
    #pragma unroll
    for (int r = 0; r < 4; ++r) rA[r] = (i0 + wy * 64 + r * 16 + l15) * 8;
    #pragma unroll
    for (int c = 0; c < 4; ++c) rB[c] = (j0 + wx * 64 + c * 16 + l15) * 8;

    // single-buffered K loop: 8 steps of K=32; TLP (4 waves/SIMD) hides latency
    #pragma unroll
    for (int s = 0; s < 8; ++s) {
        const size_t so = (size_t)s * (4u * BN * 8u);
        f16x8 a[4], b[4];
        #pragma unroll
        for (int r = 0; r < 4; ++r)
            a[r] = *reinterpret_cast<const f16x8*>(baseQ + so + (size_t)rA[r]);
        #pragma unroll
        for (int c = 0; c < 4; ++c)
            b[c] = *reinterpret_cast<const f16x8*>(baseQ + so + (size_t)rB[c]);
        #pragma unroll
        for (int c = 0; c < 4; ++c)
            #pragma unroll
            for (int r = 0; r < 4; ++r)
                acc[r][c] = __builtin_amdgcn_mfma_f32_16x16x32_f16(a[r], b[c], acc[r][c], 0, 0, 0);
    }

    // ---- epilogue: dots -> d^2 -> masked row & col stats (d^2 space; sqrt later)
    // C layout (16x16x32): col = lane&15, row = quad*4 + reg  [m89/m91, dtype-indep]
    // Iterated r-outer with per-r finalize so acc[r][*] + per-r stats die early
    // (keeps peak pressure under the 128-reg bucket).
    const int rowBase = i0 + wy * 64;
    const int colBase = j0 + wx * 64;

    int*      srhp = comb;                                   // [128]
    unsigned* srhn = reinterpret_cast<unsigned*>(comb + 128);
    int*      schp = comb + 256;
    unsigned* schn = reinterpret_cast<unsigned*>(comb + 384);
    if (tid < 128) {
        srhp[tid] = (int)HP_SENT_BITS;
        srhn[tid] = __float_as_uint(NEG_FILL_F);
        schp[tid] = (int)HP_SENT_BITS;
        schn[tid] = __float_as_uint(NEG_FILL_F);
    }
    __syncthreads();          // comb ready before any lane's atomics

    float ncol[4]; int lcol[4];
    #pragma unroll
    for (int c = 0; c < 4; ++c) {
        const int g = colBase + c * 16 + l15;
        ncol[c] = norms[g];
        lcol[c] = labels[g];
    }
    float cmax[4], cmin[4];
    #pragma unroll
    for (int c = 0; c < 4; ++c) { cmax[c] = -1.0f; cmin[c] = NEG_FILL_F; }

    #pragma unroll
    for (int r = 0; r < 4; ++r) {
        float nrow[4]; int lrow[4];
        #pragma unroll
        for (int e = 0; e < 4; ++e) {
            const int g = rowBase + r * 16 + quad * 4 + e;
            nrow[e] = norms[g];
            lrow[e] = labels[g];
        }
        float rmax[4], rmin[4];
        #pragma unroll
        for (int e = 0; e < 4; ++e) { rmax[e] = -1.0f; rmin[e] = NEG_FILL_F; }

        #pragma unroll
        for (int c = 0; c < 4; ++c) {
            const int gcol = colBase + c * 16 + l15;
            #pragma unroll
            for (int e = 0; e < 4; ++e) {
                const int grow = rowBase + r * 16 + quad * 4 + e;
                float d2 = nrow[e] + ncol[c] - 2.0f * acc[r][c][e];
                d2 = fmaxf(d2, 0.0f);            // d==0 <=> d2==0: guard-free
                if (lrow[e] == lcol[c]) {
                    if (grow != gcol) {
                        rmax[e] = fmaxf(rmax[e], d2);
                        cmax[c] = fmaxf(cmax[c], d2);
                    }
                } else {
                    rmin[e] = fminf(rmin[e], d2);
                    cmin[c] = fminf(cmin[c], d2);
                }
            }
        }
        #pragma unroll
        for (int m = 1; m <= 8; m <<= 1) {      // collapse cols (lane bits 0..3)
            #pragma unroll
            for (int e = 0; e < 4; ++e) {
                rmax[e] = fmaxf(rmax[e], __shfl_xor(rmax[e], m, 64));
                rmin[e] = fminf(rmin[e], __shfl_xor(rmin[e], m, 64));
            }
        }
        if (l15 == 0) {   // lanes 0,16,32,48 hold this r's row results per quad
            #pragma unroll
            for (int e = 0; e < 4; ++e) {
                const int lr = wy * 64 + r * 16 + quad * 4 + e;
                atomicMax(&srhp[lr], __float_as_int(rmax[e]));
                atomicMin(&srhn[lr], __float_as_uint(rmin[e]));
            }
        }
    }

    #pragma unroll
    for (int m = 16; m <= 32; m <<= 1) {        // collapse rows (quad bits)
        #pragma unroll
        for (int c = 0; c < 4; ++c) {
            cmax[c] = fmaxf(cmax[c], __shfl_xor(cmax[c], m, 64));
            cmin[c] = fminf(cmin[c], __shfl_xor(cmin[c], m, 64));
        }
    }
    if (quad == 0) {  // lanes 0..15 hold col results
        #pragma unroll
        for (int c = 0; c < 4; ++c) {
            const int lc = wx * 64 + c * 16 + l15;
            atomicMax(&schp[lc], __float_as_int(cmax[c]));
            atomicMin(&schn[lc], __float_as_uint(cmin[c]));
        }
    }
    __syncthreads();
    if (tid < 128) {
        float rp = __int_as_float(srhp[tid]);
        float rn = __uint_as_float(srhn[tid]);
        const float cp = __int_as_float(schp[tid]);
        const float cn = __uint_as_float(schn[tid]);
        if (ib == jb) {
            pHP[(size_t)jb * BN + i0 + tid] = fmaxf(rp, cp);   // diagonal: combine
            pHN[(size_t)jb * BN + i0 + tid] = fminf(rn, cn);
        } else {
            pHP[(size_t)jb * BN + i0 + tid] = rp;   // row-part -> slot jb
            pHN[(size_t)jb * BN + i0 + tid] = rn;
            pHP[(size_t)ib * BN + j0 + tid] = cp;   // col-part -> slot ib
            pHN[(size_t)ib * BN + j0 + tid] = cn;
        }
    }
}

// ------- reduce: fold 32 d^2 partial slots per row (4-way parallel per row),
//         sqrt once, accumulate loss, last block finalizes ----------------------
__global__ __launch_bounds__(256) void tl_reduce(const float* __restrict__ pHP,
                                                 const float* __restrict__ pHN,
                                                 float* __restrict__ red,
                                                 float* __restrict__ out) {
    __shared__ float shp[4][64], shn[4][64];
    const int rl = threadIdx.x & 63;                 // row within block
    const int g  = threadIdx.x >> 6;                 // slot-group 0..3 (8 slots each)
    const int i  = blockIdx.x * 64 + rl;
    float hp2 = -1.0f, hn2 = NEG_FILL_F;
    #pragma unroll
    for (int q = 0; q < 8; ++q) {
        const int s = g * 8 + q;
        hp2 = fmaxf(hp2, pHP[(size_t)s * BN + i]);   // coalesced per 64-lane group
        hn2 = fminf(hn2, pHN[(size_t)s * BN + i]);
    }
    shp[g][rl] = hp2;
    shn[g][rl] = hn2;
    __syncthreads();
    if (g == 0) {                                    // wave 0 finishes 64 rows
        #pragma unroll
        for (int k = 1; k < 4; ++k) {
            hp2 = fmaxf(hp2, shp[k][rl]);
            hn2 = fminf(hn2, shn[k][rl]);
        }
        const bool valid = (hp2 >= 0.0f) && (hn2 < NEG_FILL_F);  // has_pos && has_neg
        const float hp = sqrtf(fmaxf(hp2, 0.0f));    // sqrt(max d^2) == max d (monotone)
        const float hn = sqrtf(hn2);
        const float per = fmaxf(hp - hn + MARGIN_F, 0.0f);
        float s_ = valid ? per : 0.0f;
        float c_ = valid ? 1.0f : 0.0f;
        #pragma unroll
        for (int m = 32; m; m >>= 1) {
            s_ += __shfl_xor(s_, m, 64);
            c_ += __shfl_xor(c_, m, 64);
        }
        if (rl == 0) {
            atomicAdd(&red[0], s_);
            atomicAdd(&red[1], c_);
            __threadfence();
            const unsigned ticket = atomicAdd(reinterpret_cast<unsigned*>(&red[2]), 1u);
            if (ticket == gridDim.x - 1) {           // last block finalizes
                const float S2 = atomicAdd(&red[0], 0.0f);   // atomic read (RMW-ordered)
                const float C2 = atomicAdd(&red[1], 0.0f);
                out[0] = (C2 > 0.0f) ? (S2 / fmaxf(C2, 1.0f)) : 0.0f;
            }
        }
    }
}

extern "C" void kernel_launch(void* const* d_in, const int* in_sizes, int n_in,
                              void* d_out, int out_size, void* d_ws, size_t ws_size,
                              hipStream_t stream) {
    const float* E      = (const float*)d_in[0];
    const int*   labels = (const int*)d_in[1];

    float*  ws    = (float*)d_ws;
    float*  norms = ws;                            // [4096] f32
    float*  red   = ws + 4096;                     // [3] f32 (sum, cnt, ticket)
    float*  pHP   = ws + 8192;                     // [32][4096] f32 = 512 KB (d^2)
    float*  pHN   = ws + 8192 + NBLK * BN;         // [32][4096] f32 = 512 KB (d^2)
    ushort* Eh    = (ushort*)(ws + 8192 + 2 * NBLK * BN);  // [32][4096][8] f16 = 2 MB

    tl_prep<<<BN / 4, 256, 0, stream>>>(E, norms, red, Eh);
    tl_main<<<NPAIR, 256, 0, stream>>>(Eh, labels, norms, pHP, pHN);
    tl_reduce<<<BN / 64, 256, 0, stream>>>(pHP, pHN, red, (float*)d_out);
}